// Round 13
// baseline (970.984 us; speedup 1.0000x reference)
//
#include <hip/hip_runtime.h>
#include <stdint.h>
#include <stddef.h>

#define BN   8
#define HN   128
#define WN   128
#define HP   130
#define CLOW 128
#define CMID 256
#define KO   49

// padded key_high (bf16): [b][c][134][144], khb[b][c][y+3][x+4] = kh[b][c][y][x]
#define KHB_H 134
#define KHB_W 144
#define KHB_PLANE (KHB_H * KHB_W)   // 19296 shorts

typedef __attribute__((ext_vector_type(4))) float f32x4;
typedef __attribute__((ext_vector_type(8))) short bf16x8;

typedef __attribute__((address_space(1))) const uint8_t ga_u8;
typedef __attribute__((address_space(3))) uint8_t lds_u8;

__device__ __forceinline__ short f2bf(float f) {
    uint32_t u = __float_as_uint(f);
    u += 0x7fffu + ((u >> 16) & 1u);
    return (short)(u >> 16);
}
__device__ __forceinline__ float bf2f(short s) {
    return __uint_as_float(((uint32_t)(uint16_t)s) << 16);
}
__device__ __forceinline__ void gload16(const void* g, void* l) {
    __builtin_amdgcn_global_load_lds((ga_u8*)g, (lds_u8*)l, 16, 0, 0);
}

// ---------------------------------------------------------------------------
// Zero halo cells of all four padded [b][130][130][C] bf16 buffers.
// ---------------------------------------------------------------------------
__global__ __launch_bounds__(256) void zero_border_all_kernel(
    short* __restrict__ b0, short* __restrict__ b1,
    short* __restrict__ b2, short* __restrict__ b3) {
    const int which = blockIdx.y;
    short* buf = (which == 0) ? b0 : (which == 1) ? b1 : (which == 2) ? b2 : b3;
    const int gsh = (which < 2) ? 4 : 5;
    const int C = (which < 2) ? 128 : 256;
    int t = blockIdx.x * 256 + threadIdx.x;
    int cell = t >> gsh, g = t & ((1 << gsh) - 1);
    if (cell >= 8 * 516) return;
    int b = cell / 516, r = cell - b * 516;
    int y, x;
    if (r < 260) { y = (r >= 130) ? 129 : 0; x = (r >= 130) ? (r - 130) : r; }
    else { int j = r - 260; y = 1 + (j >> 1); x = (j & 1) ? 129 : 0; }
    uint4 z = {0u, 0u, 0u, 0u};
    *(uint4*)&buf[(((size_t)b * HP + y) * HP + x) * C + g * 8] = z;
}

// ---------------------------------------------------------------------------
// Convert NCHW fp32 -> zero-padded NHWC bf16 ([b][130][130][128]).
// ---------------------------------------------------------------------------
__global__ __launch_bounds__(256) void convert_pad_kernel(
    const float* __restrict__ src0, const float* __restrict__ src1,
    short* __restrict__ dst0, short* __restrict__ dst1) {
    __shared__ short t[128 * 136];
    const int tid = threadIdx.x;
    const int by = blockIdx.x;
    const int b = by >> 7, y = by & 127;
    const float* src = blockIdx.y ? src1 : src0;
    short* dst = blockIdx.y ? dst1 : dst0;
    #pragma unroll
    for (int k = 0; k < 16; ++k) {
        int slot = k * 256 + tid;
        int c = slot >> 5, xg = slot & 31;
        f32x4 v = *(const f32x4*)&src[(((size_t)b * CLOW + c) * HN + y) * WN + xg * 4];
        #pragma unroll
        for (int j = 0; j < 4; ++j) t[(xg * 4 + j) * 136 + c] = f2bf(v[j]);
    }
    __syncthreads();
    short* drow = dst + (((size_t)b * HP + (y + 1)) * HP + 1) * CLOW;
    #pragma unroll
    for (int k = 0; k < 8; ++k) {
        int slot = k * 256 + tid;
        int x = slot >> 4, cg = slot & 15;
        *(bf16x8*)&drow[x * CLOW + cg * 8] = *(const bf16x8*)&t[x * 136 + cg * 8];
    }
}

// ---------------------------------------------------------------------------
// Pack all weights in one launch: w_red/w2 -> tap-inner K order (CB=64);
// w3 -> bf16 [64][256] (rows 49..63 zero).
// ---------------------------------------------------------------------------
__global__ __launch_bounds__(256) void pack_w_all_kernel(
    const float* __restrict__ w1, short* __restrict__ wp1,
    const float* __restrict__ w2, short* __restrict__ wp2,
    const float* __restrict__ w3, short* __restrict__ wp3) {
    int i = blockIdx.x * 256 + threadIdx.x;
    if (i < 256 * 1152 + 256 * 4608) {
        const float* w; short* wp; int CIN, K;
        if (i < 256 * 1152) { w = w1; wp = wp1; CIN = 128; K = 1152; }
        else { i -= 256 * 1152; w = w2; wp = wp2; CIN = 512; K = 4608; }
        int cout = i / K;
        int r = i - cout * K;
        int t = r >> 6;
        int j = r & 63;
        int cb = t / 9;
        int tap = t - cb * 9;
        int cin = cb * 64 + j;
        wp[i] = f2bf(w[((size_t)cout * CIN + cin) * 9 + tap]);
    } else {
        int j = i - (256 * 1152 + 256 * 4608);
        if (j >= 64 * 256) return;
        int o = j >> 8, ch = j & 255;
        wp3[j] = (o < KO) ? f2bf(w3[o * 256 + ch]) : (short)0;
    }
}

// ---------------------------------------------------------------------------
// Unified 3x3-conv 256x256x(BK=64) kernel, B-DIRECT variant:
// A staged in LDS (double-buffered, 2x32KB); B fragments loaded straight
// from L2-hot packed weights into VGPRs (identical for all blocks -> L2
// perma-resident; lane layout lr->cout, lk->k-chunk matches the MFMA frag).
// Per tile: barrierA -> load B(t) (8 glb) -> stage A(t+1) (4 gload_lds)
// -> vmcnt(4) [A(t)+B(t) landed, A(t+1) in flight] -> barrierB -> compute.
// LDS traffic/tile drops 256KB -> 160KB (B reads+writes eliminated).
// FUSE (conv2): MFMA 1x1(256->49[+b3]) epilogue -> z[pix][64] fp32.
// ---------------------------------------------------------------------------
template <int CIN, bool OPAD, bool FUSE>
__global__ __launch_bounds__(512, 2) void conv_8ph_kernel(
    const short* __restrict__ in_a, const short* __restrict__ in_b,
    const short* __restrict__ wp, const float* __restrict__ bias,
    short* __restrict__ out_a, short* __restrict__ out_b,
    const short* __restrict__ w3p, const float* __restrict__ b3,
    float* __restrict__ z) {
    constexpr int K = 9 * CIN;
    constexpr int NT = K / 64;
    constexpr bool DUAL = (CIN == 512);
    constexpr int PST = DUAL ? 256 : CIN;
    extern __shared__ __align__(16) short lds[];
    const int tid = threadIdx.x;
    int bx = blockIdx.x;
    bx = (bx & 7) * 64 + (bx >> 3);
    const int b = bx >> 6, y0 = (bx & 63) << 1;
    const short* inA = DUAL ? in_a : (blockIdx.z ? in_b : in_a);
    const short* inB = DUAL ? in_b : inA;
    short* out = (!DUAL && blockIdx.z) ? out_b : out_a;

    const int lane = tid & 63, wv = tid >> 6;
    const int wm = wv >> 2, wn = wv & 3;
    const int lr = lane & 15, lk = lane >> 4;

    const int rA = tid >> 3, cc = tid & 7;
    const int cs = cc ^ (rA & 7);
    const int pthrA0 = rA * PST + cs * 8;
    const int pthrA1 = (rA + 64) * PST + cs * 8;
    const int dA0 = rA * 64 + cc * 8;

    const int arow = (wm * 128 + lr) * 64;
    const int cof0 = ((lk) ^ (lr & 7)) * 8;
    const int cof1 = ((4 + lk) ^ (lr & 7)) * 8;

    // per-lane global B fragment base pointers (lane lr -> cout, lk -> k-chunk)
    const short* wB[4];
    #pragma unroll
    for (int nf = 0; nf < 4; ++nf)
        wB[nf] = wp + (size_t)(wn * 64 + nf * 16 + lr) * K + (lk << 3);

    f32x4 acc[8][4];
    f32x4 zero = {0.f, 0.f, 0.f, 0.f};
    #pragma unroll
    for (int i = 0; i < 8; ++i)
        #pragma unroll
        for (int j = 0; j < 4; ++j) acc[i][j] = zero;

    auto STAGE_A = [&](int t2, short* bufA) {
        const int cb = (t2 * 57) >> 9;
        const int tap = t2 - cb * 9;
        const int ch0v = cb << 6;
        const short* src = (!DUAL || ch0v < 256) ? inA : inB;
        const int ch0 = DUAL ? (ch0v & 255) : ch0v;
        const int ky = (tap * 11) >> 5;
        const int kx = tap - ky * 3;
        const short* s0 = src + ((size_t)(b * HP + (y0 + ky)) * HP + kx) * PST + ch0;
        gload16(s0 + pthrA0, bufA + dA0);                          // row0 px 0..63
        gload16(s0 + (HP * PST) + pthrA0, bufA + 128 * 64 + dA0);  // row1 px 0..63
        gload16(s0 + pthrA1, bufA + 64 * 64 + dA0);                // row0 px 64..127
        gload16(s0 + (HP * PST) + pthrA1, bufA + 192 * 64 + dA0);  // row1 px 64..127
    };

    auto LDA = [&](const short* bufA, int mh, bf16x8 (&a)[4][2]) {
        #pragma unroll
        for (int i = 0; i < 4; ++i) {
            const int ro = arow + (mh * 64 + i * 16) * 64;
            a[i][0] = *(const bf16x8*)(bufA + ro + cof0);
            a[i][1] = *(const bf16x8*)(bufA + ro + cof1);
        }
    };

#define MFMA_Q(A_, B_, MH, NH) do { \
    _Pragma("unroll") \
    for (int i_ = 0; i_ < 4; ++i_) { \
        _Pragma("unroll") \
        for (int j_ = 0; j_ < 2; ++j_) { \
            acc[(MH)*4+i_][(NH)*2+j_] = __builtin_amdgcn_mfma_f32_16x16x32_bf16( \
                A_[i_][0], B_[(NH)*2+j_][0], acc[(MH)*4+i_][(NH)*2+j_], 0, 0, 0); \
            acc[(MH)*4+i_][(NH)*2+j_] = __builtin_amdgcn_mfma_f32_16x16x32_bf16( \
                A_[i_][1], B_[(NH)*2+j_][1], acc[(MH)*4+i_][(NH)*2+j_], 0, 0, 0); \
        } \
    } } while (0)

    short* const A0 = lds;
    short* const A1 = lds + 16384;

    // prologue: stage tile 0
    STAGE_A(0, A0);

    auto TILE = [&](int t, short* bufA, short* nA) {
        // barrier A: all waves done reading nA (tile t-1) -> restage ok
        __builtin_amdgcn_s_barrier();
        __builtin_amdgcn_sched_barrier(0);
        // load B(t) fragments from global (L2-hot)
        bf16x8 bf[4][2];
        #pragma unroll
        for (int nf = 0; nf < 4; ++nf) {
            bf[nf][0] = *(const bf16x8*)(wB[nf] + t * 64);
            bf[nf][1] = *(const bf16x8*)(wB[nf] + t * 64 + 32);
        }
        __builtin_amdgcn_sched_barrier(0);
        const int t1 = t + 1;
        if (t1 < NT) {
            STAGE_A(t1, nA);
            __builtin_amdgcn_sched_barrier(0);
            asm volatile("s_waitcnt vmcnt(4)" ::: "memory");  // A(t)+B(t) landed
        } else {
            __builtin_amdgcn_sched_barrier(0);
            asm volatile("s_waitcnt vmcnt(0)" ::: "memory");
        }
        __builtin_amdgcn_sched_barrier(0);
        // barrier B: publishes -> ALL waves' tile-t A staging landed
        __builtin_amdgcn_s_barrier();
        __builtin_amdgcn_sched_barrier(0);
        bf16x8 ar[4][2];
        LDA(bufA, 0, ar);
        __builtin_amdgcn_s_setprio(1);
        MFMA_Q(ar, bf, 0, 0);
        MFMA_Q(ar, bf, 0, 1);
        __builtin_amdgcn_s_setprio(0);
        LDA(bufA, 1, ar);
        __builtin_amdgcn_s_setprio(1);
        MFMA_Q(ar, bf, 1, 0);
        MFMA_Q(ar, bf, 1, 1);
        __builtin_amdgcn_s_setprio(0);
    };

    for (int t = 0; t < NT; t += 2) {
        TILE(t,     A0, A1);
        TILE(t + 1, A1, A0);
    }
#undef MFMA_Q

    float bvs[4];
    #pragma unroll
    for (int nf = 0; nf < 4; ++nf) bvs[nf] = bias[wn * 64 + nf * 16 + lr];

    if constexpr (!FUSE) {
        #pragma unroll
        for (int mf = 0; mf < 8; ++mf) {
            #pragma unroll
            for (int rr = 0; rr < 4; ++rr) {
                const int p = wm * 128 + mf * 16 + lk * 4 + rr;
                const int y = y0 + (p >> 7), x = p & 127;
                short* op;
                if (OPAD)
                    op = out + ((size_t)(b * HP + (y + 1)) * HP + (x + 1)) * CMID + wn * 64 + lr;
                else
                    op = out + ((size_t)((b * HN + y) * WN + x)) * CMID + wn * 64 + lr;
                #pragma unroll
                for (int nf = 0; nf < 4; ++nf)
                    op[nf * 16] = f2bf(fmaxf(acc[mf][nf][rr] + bvs[nf], 0.f));
            }
        }
    } else {
        // ---- MFMA 1x1(256->49) epilogue: logits -> z[pix][64] fp32 ----
        __syncthreads();                               // drains counters; LDS free
        short* const Xh  = lds;                        // [128px][256ch] bf16 swz
        short* const W3s = lds + 32768;                // [64o][256ch] bf16 swz

        #pragma unroll
        for (int sweep = 0; sweep < 4; ++sweep) {
            const int s = sweep * 512 + tid;
            const int o = s >> 5, c = s & 31;
            gload16(w3p + o * 256 + ((c ^ (o & 7)) << 3), W3s + s * 8);
        }

        const int oo = wn * 16 + lr;
        const float b3v = (oo < KO) ? b3[oo] : 0.f;

        #pragma unroll 1
        for (int r = 0; r < 2; ++r) {
            if (wm == r) {
                #pragma unroll
                for (int nf = 0; nf < 4; ++nf) {
                    const int ch = wn * 64 + nf * 16 + lr;
                    const int ck = ch >> 3, el = ch & 7;
                    #pragma unroll
                    for (int mf = 0; mf < 8; ++mf) {
                        #pragma unroll
                        for (int rr = 0; rr < 4; ++rr) {
                            const int px = mf * 16 + lk * 4 + rr;
                            Xh[px * 256 + ((ck ^ (px & 7)) << 3) + el] =
                                f2bf(fmaxf(acc[mf][nf][rr] + bvs[nf], 0.f));
                        }
                    }
                }
            }
            __syncthreads();
            f32x4 a2[4];
            #pragma unroll
            for (int m = 0; m < 4; ++m) {
                a2[m][0] = b3v; a2[m][1] = b3v; a2[m][2] = b3v; a2[m][3] = b3v;
            }
            #pragma unroll
            for (int ks = 0; ks < 8; ++ks) {
                const bf16x8 bfr =
                    *(const bf16x8*)&W3s[oo * 256 + (((ks * 4 + lk) ^ (oo & 7)) << 3)];
                #pragma unroll
                for (int m = 0; m < 4; ++m) {
                    const int px = wm * 64 + m * 16 + lr;
                    const bf16x8 afr =
                        *(const bf16x8*)&Xh[px * 256 + (((ks * 4 + lk) ^ (px & 7)) << 3)];
                    a2[m] = __builtin_amdgcn_mfma_f32_16x16x32_bf16(afr, bfr, a2[m], 0, 0, 0);
                }
            }
            float* zp = z + ((size_t)(b * 16384 + (y0 + r) * 128)) * 64;
            #pragma unroll
            for (int m = 0; m < 4; ++m) {
                #pragma unroll
                for (int r2 = 0; r2 < 4; ++r2) {
                    const int px = wm * 64 + m * 16 + lk * 4 + r2;
                    zp[px * 64 + oo] = a2[m][r2];
                }
            }
            if (r == 0) __syncthreads();
        }
    }
}

// ---------------------------------------------------------------------------
// Pad key_high NCHW fp32 -> bf16 [b][c][134][144] with zero halo, vectorized:
// per (row,group) unit: two aligned f32x4 loads + one bf16x8 store.
// khb x = kh x + 4, so group g covers kh x in [g*8-4, g*8+4) .. +4.
// ---------------------------------------------------------------------------
__global__ __launch_bounds__(256) void pad_kh_kernel(
    const float* __restrict__ kh, short* __restrict__ khb) {
    const int bc = blockIdx.x;
    const float* src = kh + (size_t)bc * (HN * WN);
    short* dst = khb + (size_t)bc * KHB_PLANE;
    for (int u = threadIdx.x; u < KHB_H * 18; u += 256) {
        const int yy = (u * 3641) >> 16;          // u/18 for u < 2412
        const int g = u - yy * 18;
        const int ys = yy - 3;
        const int xb = g * 8 - 4;                 // kh x of output elem 0
        f32x4 lo = {0.f, 0.f, 0.f, 0.f}, hi = {0.f, 0.f, 0.f, 0.f};
        if ((unsigned)ys < 128u) {
            const float* row = src + (ys << 7);
            if ((unsigned)xb < 125u)       lo = *(const f32x4*)(row + xb);      // xb>=0, xb+3<128
            if ((unsigned)(xb + 4) < 125u) hi = *(const f32x4*)(row + xb + 4);
        }
        bf16x8 v;
        #pragma unroll
        for (int t = 0; t < 4; ++t) { v[t] = f2bf(lo[t]); v[t + 4] = f2bf(hi[t]); }
        *(bf16x8*)&dst[yy * KHB_W + g * 8] = v;
    }
}

// ---------------------------------------------------------------------------
// SVC v4: fused softmax (from z logits) + spatially-variant conv (unchanged).
// ---------------------------------------------------------------------------
__global__ __launch_bounds__(256) void svc4_kernel(
    const float* __restrict__ z, const short* __restrict__ khb,
    float* __restrict__ out) {
    __shared__ float a_s[KO * 64];
    const int tid = threadIdx.x;
    int by = blockIdx.y;
    by = (by & 7) * 128 + (by >> 3);
    const int b = by >> 7, y = by & 127;
    const int x0 = blockIdx.x * 64;

    {
        const int px = tid >> 2, l = tid & 3;
        const float* zp = z + ((size_t)(b * 16384 + (y << 7) + x0 + px)) * 64 + l * 16;
        float v[16];
        #pragma unroll
        for (int q = 0; q < 4; ++q) {
            f32x4 t4 = *(const f32x4*)&zp[q * 4];
            v[q * 4 + 0] = fmaxf(t4[0], 0.f);
            v[q * 4 + 1] = fmaxf(t4[1], 0.f);
            v[q * 4 + 2] = fmaxf(t4[2], 0.f);
            v[q * 4 + 3] = fmaxf(t4[3], 0.f);
        }
        #pragma unroll
        for (int j = 1; j < 16; ++j) if (l == 3) v[j] = -1e30f;
        float m = v[0];
        #pragma unroll
        for (int j = 1; j < 16; ++j) m = fmaxf(m, v[j]);
        m = fmaxf(m, __shfl_xor(m, 1, 64));
        m = fmaxf(m, __shfl_xor(m, 2, 64));
        float s = 0.f;
        #pragma unroll
        for (int j = 0; j < 16; ++j) { v[j] = __expf(v[j] - m); s += v[j]; }
        s += __shfl_xor(s, 1, 64);
        s += __shfl_xor(s, 2, 64);
        const float inv = 1.f / s;
        #pragma unroll
        for (int j = 0; j < 16; ++j) {
            const int o = l * 16 + j;
            if (o < KO) a_s[o * 64 + px] = v[j] * inv;
        }
    }
    __syncthreads();

    const int ci = tid >> 3;
    const int pg = tid & 7;
    const int p0 = x0 + pg * 8;

    float acc[8][8];
    #pragma unroll
    for (int c = 0; c < 8; ++c)
        #pragma unroll
        for (int j = 0; j < 8; ++j) acc[c][j] = 0.f;

    const short* kbase = khb + (((size_t)b * 256 + ci) * KHB_H + y) * KHB_W + p0;

    #pragma unroll 1
    for (int dy = 0; dy < 7; ++dy) {
        f32x4 av[14];
        #pragma unroll
        for (int dx = 0; dx < 7; ++dx) {
            av[dx * 2]     = *(const f32x4*)&a_s[(dy * 7 + dx) * 64 + pg * 8];
            av[dx * 2 + 1] = *(const f32x4*)&a_s[(dy * 7 + dx) * 64 + pg * 8 + 4];
        }
        const short* krow = kbase + dy * KHB_W;
        #pragma unroll
        for (int c = 0; c < 8; ++c) {
            const short* kp = krow + (size_t)c * 32 * KHB_PLANE;
            bf16x8 k0 = *(const bf16x8*)(kp);
            bf16x8 k1 = *(const bf16x8*)(kp + 8);
            float win[16];
            #pragma unroll
            for (int t = 0; t < 8; ++t) { win[t] = bf2f(k0[t]); win[t + 8] = bf2f(k1[t]); }
            #pragma unroll
            for (int dx = 0; dx < 7; ++dx) {
                #pragma unroll
                for (int j = 0; j < 8; ++j)
                    acc[c][j] = fmaf(win[j + dx + 1], av[dx * 2 + (j >> 2)][j & 3],
                                     acc[c][j]);
            }
        }
    }

    #pragma unroll
    for (int c = 0; c < 8; ++c) {
        float* op = out + (((size_t)b * 256 + ci + c * 32) << 14) + (y << 7) + p0;
        f32x4 r0 = {acc[c][0], acc[c][1], acc[c][2], acc[c][3]};
        f32x4 r1 = {acc[c][4], acc[c][5], acc[c][6], acc[c][7]};
        *(f32x4*)op = r0;
        *(f32x4*)(op + 4) = r1;
    }
}

// ---------------------------------------------------------------------------
extern "C" void kernel_launch(void* const* d_in, const int* in_sizes, int n_in,
                              void* d_out, int out_size, void* d_ws, size_t ws_size,
                              hipStream_t stream) {
    (void)in_sizes; (void)n_in; (void)out_size; (void)ws_size;
    const float* cur_low  = (const float*)d_in[0];
    const float* key_low  = (const float*)d_in[1];
    const float* key_high = (const float*)d_in[2];
    const float* w_red    = (const float*)d_in[3];
    const float* b_red    = (const float*)d_in[4];
    const float* w2       = (const float*)d_in[5];
    const float* b2       = (const float*)d_in[6];
    const float* w3       = (const float*)d_in[7];
    const float* b3       = (const float*)d_in[8];
    float* out = (float*)d_out;
    char* ws = (char*)d_ws;

    const size_t SZ_XPAD = (size_t)BN * HP * HP * CLOW * 2;
    const size_t SZ_YPAD = (size_t)BN * HP * HP * CMID * 2;
    short* xpadc = (short*)(ws);
    short* xpadk = (short*)(ws + SZ_XPAD);
    short* ypadc = (short*)(ws + 2 * SZ_XPAD);
    short* ypadk = (short*)(ws + 2 * SZ_XPAD + SZ_YPAD);
    short* w1p   = (short*)(ws + 2 * SZ_XPAD + 2 * SZ_YPAD);
    short* w2p   = w1p + (size_t)256 * 1152;
    float* z     = (float*)(ws);
    short* khb   = (short*)(ws + 2 * SZ_XPAD);
    short* w3p   = (short*)((char*)d_out + (size_t)134217728 - 32768);

    hipFuncSetAttribute((const void*)conv_8ph_kernel<128, true, false>,
                        hipFuncAttributeMaxDynamicSharedMemorySize, 65536);
    hipFuncSetAttribute((const void*)conv_8ph_kernel<512, false, true>,
                        hipFuncAttributeMaxDynamicSharedMemorySize, 98304);

    zero_border_all_kernel<<<dim3(516, 4), 256, 0, stream>>>(xpadc, xpadk, ypadc, ypadk);
    convert_pad_kernel<<<dim3(1024, 2), 256, 0, stream>>>(cur_low, key_low, xpadc, xpadk);
    pack_w_all_kernel<<<(256 * (1152 + 4608) + 64 * 256 + 255) / 256, 256, 0, stream>>>(
        w_red, w1p, w2, w2p, w3, w3p);

    conv_8ph_kernel<128, true, false><<<dim3(512, 1, 2), 512, 65536, stream>>>(
        xpadc, xpadk, w1p, b_red, ypadc, ypadk, nullptr, nullptr, nullptr);

    conv_8ph_kernel<512, false, true><<<dim3(512, 1, 1), 512, 98304, stream>>>(
        ypadc, ypadk, w2p, b2, nullptr, nullptr, w3p, b3, z);

    pad_kh_kernel<<<2048, 256, 0, stream>>>(key_high, khb);
    svc4_kernel<<<dim3(2, 1024), 256, 0, stream>>>(z, khb, out);
}

// Round 14
// 877.292 us; speedup vs baseline: 1.1068x; 1.1068x over previous
//
#include <hip/hip_runtime.h>
#include <stdint.h>
#include <stddef.h>

#define BN   8
#define HN   128
#define WN   128
#define HP   130
#define CLOW 128
#define CMID 256
#define KO   49

// padded key_high (bf16): [b][c][134][144], khb[b][c][y+3][x+4] = kh[b][c][y][x]
#define KHB_H 134
#define KHB_W 144
#define KHB_PLANE (KHB_H * KHB_W)   // 19296 shorts

typedef __attribute__((ext_vector_type(4))) float f32x4;
typedef __attribute__((ext_vector_type(8))) short bf16x8;

typedef __attribute__((address_space(1))) const uint8_t ga_u8;
typedef __attribute__((address_space(3))) uint8_t lds_u8;

__device__ __forceinline__ short f2bf(float f) {
    uint32_t u = __float_as_uint(f);
    u += 0x7fffu + ((u >> 16) & 1u);
    return (short)(u >> 16);
}
__device__ __forceinline__ float bf2f(short s) {
    return __uint_as_float(((uint32_t)(uint16_t)s) << 16);
}
__device__ __forceinline__ void gload16(const void* g, void* l) {
    __builtin_amdgcn_global_load_lds((ga_u8*)g, (lds_u8*)l, 16, 0, 0);
}

// ---------------------------------------------------------------------------
// Zero halo cells of all four padded [b][130][130][C] bf16 buffers.
// ---------------------------------------------------------------------------
__global__ __launch_bounds__(256) void zero_border_all_kernel(
    short* __restrict__ b0, short* __restrict__ b1,
    short* __restrict__ b2, short* __restrict__ b3) {
    const int which = blockIdx.y;
    short* buf = (which == 0) ? b0 : (which == 1) ? b1 : (which == 2) ? b2 : b3;
    const int gsh = (which < 2) ? 4 : 5;
    const int C = (which < 2) ? 128 : 256;
    int t = blockIdx.x * 256 + threadIdx.x;
    int cell = t >> gsh, g = t & ((1 << gsh) - 1);
    if (cell >= 8 * 516) return;
    int b = cell / 516, r = cell - b * 516;
    int y, x;
    if (r < 260) { y = (r >= 130) ? 129 : 0; x = (r >= 130) ? (r - 130) : r; }
    else { int j = r - 260; y = 1 + (j >> 1); x = (j & 1) ? 129 : 0; }
    uint4 z = {0u, 0u, 0u, 0u};
    *(uint4*)&buf[(((size_t)b * HP + y) * HP + x) * C + g * 8] = z;
}

// ---------------------------------------------------------------------------
// Convert NCHW fp32 -> zero-padded NHWC bf16 ([b][130][130][128]).
// ---------------------------------------------------------------------------
__global__ __launch_bounds__(256) void convert_pad_kernel(
    const float* __restrict__ src0, const float* __restrict__ src1,
    short* __restrict__ dst0, short* __restrict__ dst1) {
    __shared__ short t[128 * 136];
    const int tid = threadIdx.x;
    const int by = blockIdx.x;
    const int b = by >> 7, y = by & 127;
    const float* src = blockIdx.y ? src1 : src0;
    short* dst = blockIdx.y ? dst1 : dst0;
    #pragma unroll
    for (int k = 0; k < 16; ++k) {
        int slot = k * 256 + tid;
        int c = slot >> 5, xg = slot & 31;
        f32x4 v = *(const f32x4*)&src[(((size_t)b * CLOW + c) * HN + y) * WN + xg * 4];
        #pragma unroll
        for (int j = 0; j < 4; ++j) t[(xg * 4 + j) * 136 + c] = f2bf(v[j]);
    }
    __syncthreads();
    short* drow = dst + (((size_t)b * HP + (y + 1)) * HP + 1) * CLOW;
    #pragma unroll
    for (int k = 0; k < 8; ++k) {
        int slot = k * 256 + tid;
        int x = slot >> 4, cg = slot & 15;
        *(bf16x8*)&drow[x * CLOW + cg * 8] = *(const bf16x8*)&t[x * 136 + cg * 8];
    }
}

// ---------------------------------------------------------------------------
// Pack all weights in one launch: w_red/w2 -> tap-inner K order (CB=64);
// w3 -> bf16 [64][256] (rows 49..63 zero).
// ---------------------------------------------------------------------------
__global__ __launch_bounds__(256) void pack_w_all_kernel(
    const float* __restrict__ w1, short* __restrict__ wp1,
    const float* __restrict__ w2, short* __restrict__ wp2,
    const float* __restrict__ w3, short* __restrict__ wp3) {
    int i = blockIdx.x * 256 + threadIdx.x;
    if (i < 256 * 1152 + 256 * 4608) {
        const float* w; short* wp; int CIN, K;
        if (i < 256 * 1152) { w = w1; wp = wp1; CIN = 128; K = 1152; }
        else { i -= 256 * 1152; w = w2; wp = wp2; CIN = 512; K = 4608; }
        int cout = i / K;
        int r = i - cout * K;
        int t = r >> 6;
        int j = r & 63;
        int cb = t / 9;
        int tap = t - cb * 9;
        int cin = cb * 64 + j;
        wp[i] = f2bf(w[((size_t)cout * CIN + cin) * 9 + tap]);
    } else {
        int j = i - (256 * 1152 + 256 * 4608);
        if (j >= 64 * 256) return;
        int o = j >> 8, ch = j & 255;
        wp3[j] = (o < KO) ? f2bf(w3[o * 256 + ch]) : (short)0;
    }
}

// ---------------------------------------------------------------------------
// Unified 3x3-conv 256x256x(BK=64) kernel, B-DIRECT + PREFETCH variant:
// A staged in LDS (double-buffered 2x32KB, lead-1); B fragments loaded
// straight from L2-hot packed weights into a DOUBLE register set, also
// lead-1: TILE(t) issues B(t+1)->bfNext and A(t+1)->nA (12 VMEM ops), then
// vmcnt(12) waits exactly for tile t's B+A (issued in tile t-1, a full
// tile of latency cover). barrier B publishes cross-wave A staging.
// FUSE (conv2): MFMA 1x1(256->49[+b3]) epilogue -> z[pix][64] fp32.
// ---------------------------------------------------------------------------
template <int CIN, bool OPAD, bool FUSE>
__global__ __launch_bounds__(512, 2) void conv_8ph_kernel(
    const short* __restrict__ in_a, const short* __restrict__ in_b,
    const short* __restrict__ wp, const float* __restrict__ bias,
    short* __restrict__ out_a, short* __restrict__ out_b,
    const short* __restrict__ w3p, const float* __restrict__ b3,
    float* __restrict__ z) {
    constexpr int K = 9 * CIN;
    constexpr int NT = K / 64;
    constexpr bool DUAL = (CIN == 512);
    constexpr int PST = DUAL ? 256 : CIN;
    extern __shared__ __align__(16) short lds[];
    const int tid = threadIdx.x;
    int bx = blockIdx.x;
    bx = (bx & 7) * 64 + (bx >> 3);
    const int b = bx >> 6, y0 = (bx & 63) << 1;
    const short* inA = DUAL ? in_a : (blockIdx.z ? in_b : in_a);
    const short* inB = DUAL ? in_b : inA;
    short* out = (!DUAL && blockIdx.z) ? out_b : out_a;

    const int lane = tid & 63, wv = tid >> 6;
    const int wm = wv >> 2, wn = wv & 3;
    const int lr = lane & 15, lk = lane >> 4;

    const int rA = tid >> 3, cc = tid & 7;
    const int cs = cc ^ (rA & 7);
    const int pthrA0 = rA * PST + cs * 8;
    const int pthrA1 = (rA + 64) * PST + cs * 8;
    const int dA0 = rA * 64 + cc * 8;

    const int arow = (wm * 128 + lr) * 64;
    const int cof0 = ((lk) ^ (lr & 7)) * 8;
    const int cof1 = ((4 + lk) ^ (lr & 7)) * 8;

    // per-lane global B fragment base pointers (lane lr -> cout, lk -> k-chunk)
    const short* wB[4];
    #pragma unroll
    for (int nf = 0; nf < 4; ++nf)
        wB[nf] = wp + (size_t)(wn * 64 + nf * 16 + lr) * K + (lk << 3);

    f32x4 acc[8][4];
    f32x4 zero = {0.f, 0.f, 0.f, 0.f};
    #pragma unroll
    for (int i = 0; i < 8; ++i)
        #pragma unroll
        for (int j = 0; j < 4; ++j) acc[i][j] = zero;

    auto STAGE_A = [&](int t2, short* bufA) {
        const int cb = (t2 * 57) >> 9;
        const int tap = t2 - cb * 9;
        const int ch0v = cb << 6;
        const short* src = (!DUAL || ch0v < 256) ? inA : inB;
        const int ch0 = DUAL ? (ch0v & 255) : ch0v;
        const int ky = (tap * 11) >> 5;
        const int kx = tap - ky * 3;
        const short* s0 = src + ((size_t)(b * HP + (y0 + ky)) * HP + kx) * PST + ch0;
        gload16(s0 + pthrA0, bufA + dA0);
        gload16(s0 + (HP * PST) + pthrA0, bufA + 128 * 64 + dA0);
        gload16(s0 + pthrA1, bufA + 64 * 64 + dA0);
        gload16(s0 + (HP * PST) + pthrA1, bufA + 192 * 64 + dA0);
    };

    auto LOADB = [&](int t2, bf16x8 (&bf)[4][2]) {
        #pragma unroll
        for (int nf = 0; nf < 4; ++nf) {
            bf[nf][0] = *(const bf16x8*)(wB[nf] + t2 * 64);
            bf[nf][1] = *(const bf16x8*)(wB[nf] + t2 * 64 + 32);
        }
    };

    auto LDA = [&](const short* bufA, int mh, bf16x8 (&a)[4][2]) {
        #pragma unroll
        for (int i = 0; i < 4; ++i) {
            const int ro = arow + (mh * 64 + i * 16) * 64;
            a[i][0] = *(const bf16x8*)(bufA + ro + cof0);
            a[i][1] = *(const bf16x8*)(bufA + ro + cof1);
        }
    };

#define MFMA_Q(A_, B_, MH, NH) do { \
    _Pragma("unroll") \
    for (int i_ = 0; i_ < 4; ++i_) { \
        _Pragma("unroll") \
        for (int j_ = 0; j_ < 2; ++j_) { \
            acc[(MH)*4+i_][(NH)*2+j_] = __builtin_amdgcn_mfma_f32_16x16x32_bf16( \
                A_[i_][0], B_[(NH)*2+j_][0], acc[(MH)*4+i_][(NH)*2+j_], 0, 0, 0); \
            acc[(MH)*4+i_][(NH)*2+j_] = __builtin_amdgcn_mfma_f32_16x16x32_bf16( \
                A_[i_][1], B_[(NH)*2+j_][1], acc[(MH)*4+i_][(NH)*2+j_], 0, 0, 0); \
        } \
    } } while (0)

    short* const A0 = lds;
    short* const A1 = lds + 16384;

    bf16x8 bfS0[4][2], bfS1[4][2];

    // prologue: B(0) + A(0) in flight (12 VMEM ops)
    LOADB(0, bfS0);
    STAGE_A(0, A0);

    auto TILE = [&](int t, short* bufA, short* nA,
                    bf16x8 (&bfCur)[4][2], bf16x8 (&bfNext)[4][2]) {
        // barrier A: all waves done reading nA (tile t-1) -> restage ok
        __builtin_amdgcn_s_barrier();
        __builtin_amdgcn_sched_barrier(0);
        const int t1 = t + 1;
        if (t1 < NT) {
            LOADB(t1, bfNext);          // 8 VGPR loads (L2-hot)
            STAGE_A(t1, nA);            // 4 gload_lds
            __builtin_amdgcn_sched_barrier(0);
            // waits for tile t's B+A (issued in tile t-1); leaves 12 in flight
            asm volatile("s_waitcnt vmcnt(12)" ::: "memory");
        } else {
            __builtin_amdgcn_sched_barrier(0);
            asm volatile("s_waitcnt vmcnt(0)" ::: "memory");
        }
        __builtin_amdgcn_sched_barrier(0);
        // barrier B: publishes -> ALL waves' tile-t A staging landed
        __builtin_amdgcn_s_barrier();
        __builtin_amdgcn_sched_barrier(0);
        bf16x8 ar[4][2];
        LDA(bufA, 0, ar);
        __builtin_amdgcn_s_setprio(1);
        MFMA_Q(ar, bfCur, 0, 0);
        MFMA_Q(ar, bfCur, 0, 1);
        __builtin_amdgcn_s_setprio(0);
        LDA(bufA, 1, ar);
        __builtin_amdgcn_s_setprio(1);
        MFMA_Q(ar, bfCur, 1, 0);
        MFMA_Q(ar, bfCur, 1, 1);
        __builtin_amdgcn_s_setprio(0);
    };

    for (int t = 0; t < NT; t += 2) {
        TILE(t,     A0, A1, bfS0, bfS1);
        TILE(t + 1, A1, A0, bfS1, bfS0);
    }
#undef MFMA_Q

    float bvs[4];
    #pragma unroll
    for (int nf = 0; nf < 4; ++nf) bvs[nf] = bias[wn * 64 + nf * 16 + lr];

    if constexpr (!FUSE) {
        #pragma unroll
        for (int mf = 0; mf < 8; ++mf) {
            #pragma unroll
            for (int rr = 0; rr < 4; ++rr) {
                const int p = wm * 128 + mf * 16 + lk * 4 + rr;
                const int y = y0 + (p >> 7), x = p & 127;
                short* op;
                if (OPAD)
                    op = out + ((size_t)(b * HP + (y + 1)) * HP + (x + 1)) * CMID + wn * 64 + lr;
                else
                    op = out + ((size_t)((b * HN + y) * WN + x)) * CMID + wn * 64 + lr;
                #pragma unroll
                for (int nf = 0; nf < 4; ++nf)
                    op[nf * 16] = f2bf(fmaxf(acc[mf][nf][rr] + bvs[nf], 0.f));
            }
        }
    } else {
        // ---- MFMA 1x1(256->49) epilogue: logits -> z[pix][64] fp32 ----
        __syncthreads();                               // drains; LDS free
        short* const Xh  = lds;                        // [128px][256ch] bf16 swz
        short* const W3s = lds + 32768;                // [64o][256ch] bf16 swz

        #pragma unroll
        for (int sweep = 0; sweep < 4; ++sweep) {
            const int s = sweep * 512 + tid;
            const int o = s >> 5, c = s & 31;
            gload16(w3p + o * 256 + ((c ^ (o & 7)) << 3), W3s + s * 8);
        }

        const int oo = wn * 16 + lr;
        const float b3v = (oo < KO) ? b3[oo] : 0.f;

        #pragma unroll 1
        for (int r = 0; r < 2; ++r) {
            if (wm == r) {
                #pragma unroll
                for (int nf = 0; nf < 4; ++nf) {
                    const int ch = wn * 64 + nf * 16 + lr;
                    const int ck = ch >> 3, el = ch & 7;
                    #pragma unroll
                    for (int mf = 0; mf < 8; ++mf) {
                        #pragma unroll
                        for (int rr = 0; rr < 4; ++rr) {
                            const int px = mf * 16 + lk * 4 + rr;
                            Xh[px * 256 + ((ck ^ (px & 7)) << 3) + el] =
                                f2bf(fmaxf(acc[mf][nf][rr] + bvs[nf], 0.f));
                        }
                    }
                }
            }
            __syncthreads();
            f32x4 a2[4];
            #pragma unroll
            for (int m = 0; m < 4; ++m) {
                a2[m][0] = b3v; a2[m][1] = b3v; a2[m][2] = b3v; a2[m][3] = b3v;
            }
            #pragma unroll
            for (int ks = 0; ks < 8; ++ks) {
                const bf16x8 bfr =
                    *(const bf16x8*)&W3s[oo * 256 + (((ks * 4 + lk) ^ (oo & 7)) << 3)];
                #pragma unroll
                for (int m = 0; m < 4; ++m) {
                    const int px = wm * 64 + m * 16 + lr;
                    const bf16x8 afr =
                        *(const bf16x8*)&Xh[px * 256 + (((ks * 4 + lk) ^ (px & 7)) << 3)];
                    a2[m] = __builtin_amdgcn_mfma_f32_16x16x32_bf16(afr, bfr, a2[m], 0, 0, 0);
                }
            }
            float* zp = z + ((size_t)(b * 16384 + (y0 + r) * 128)) * 64;
            #pragma unroll
            for (int m = 0; m < 4; ++m) {
                #pragma unroll
                for (int r2 = 0; r2 < 4; ++r2) {
                    const int px = wm * 64 + m * 16 + lk * 4 + r2;
                    zp[px * 64 + oo] = a2[m][r2];
                }
            }
            if (r == 0) __syncthreads();
        }
    }
}

// ---------------------------------------------------------------------------
// Pad key_high NCHW fp32 -> bf16 [b][c][134][144] with zero halo, vectorized.
// ---------------------------------------------------------------------------
__global__ __launch_bounds__(256) void pad_kh_kernel(
    const float* __restrict__ kh, short* __restrict__ khb) {
    const int bc = blockIdx.x;
    const float* src = kh + (size_t)bc * (HN * WN);
    short* dst = khb + (size_t)bc * KHB_PLANE;
    for (int u = threadIdx.x; u < KHB_H * 18; u += 256) {
        const int yy = (u * 3641) >> 16;          // u/18 for u < 2412
        const int g = u - yy * 18;
        const int ys = yy - 3;
        const int xb = g * 8 - 4;
        f32x4 lo = {0.f, 0.f, 0.f, 0.f}, hi = {0.f, 0.f, 0.f, 0.f};
        if ((unsigned)ys < 128u) {
            const float* row = src + (ys << 7);
            if ((unsigned)xb < 125u)       lo = *(const f32x4*)(row + xb);
            if ((unsigned)(xb + 4) < 125u) hi = *(const f32x4*)(row + xb + 4);
        }
        bf16x8 v;
        #pragma unroll
        for (int t = 0; t < 4; ++t) { v[t] = f2bf(lo[t]); v[t + 4] = f2bf(hi[t]); }
        *(bf16x8*)&dst[yy * KHB_W + g * 8] = v;
    }
}

// ---------------------------------------------------------------------------
// SVC v4: fused softmax (from z logits) + spatially-variant conv (unchanged).
// ---------------------------------------------------------------------------
__global__ __launch_bounds__(256) void svc4_kernel(
    const float* __restrict__ z, const short* __restrict__ khb,
    float* __restrict__ out) {
    __shared__ float a_s[KO * 64];
    const int tid = threadIdx.x;
    int by = blockIdx.y;
    by = (by & 7) * 128 + (by >> 3);
    const int b = by >> 7, y = by & 127;
    const int x0 = blockIdx.x * 64;

    {
        const int px = tid >> 2, l = tid & 3;
        const float* zp = z + ((size_t)(b * 16384 + (y << 7) + x0 + px)) * 64 + l * 16;
        float v[16];
        #pragma unroll
        for (int q = 0; q < 4; ++q) {
            f32x4 t4 = *(const f32x4*)&zp[q * 4];
            v[q * 4 + 0] = fmaxf(t4[0], 0.f);
            v[q * 4 + 1] = fmaxf(t4[1], 0.f);
            v[q * 4 + 2] = fmaxf(t4[2], 0.f);
            v[q * 4 + 3] = fmaxf(t4[3], 0.f);
        }
        #pragma unroll
        for (int j = 1; j < 16; ++j) if (l == 3) v[j] = -1e30f;
        float m = v[0];
        #pragma unroll
        for (int j = 1; j < 16; ++j) m = fmaxf(m, v[j]);
        m = fmaxf(m, __shfl_xor(m, 1, 64));
        m = fmaxf(m, __shfl_xor(m, 2, 64));
        float s = 0.f;
        #pragma unroll
        for (int j = 0; j < 16; ++j) { v[j] = __expf(v[j] - m); s += v[j]; }
        s += __shfl_xor(s, 1, 64);
        s += __shfl_xor(s, 2, 64);
        const float inv = 1.f / s;
        #pragma unroll
        for (int j = 0; j < 16; ++j) {
            const int o = l * 16 + j;
            if (o < KO) a_s[o * 64 + px] = v[j] * inv;
        }
    }
    __syncthreads();

    const int ci = tid >> 3;
    const int pg = tid & 7;
    const int p0 = x0 + pg * 8;

    float acc[8][8];
    #pragma unroll
    for (int c = 0; c < 8; ++c)
        #pragma unroll
        for (int j = 0; j < 8; ++j) acc[c][j] = 0.f;

    const short* kbase = khb + (((size_t)b * 256 + ci) * KHB_H + y) * KHB_W + p0;

    #pragma unroll 1
    for (int dy = 0; dy < 7; ++dy) {
        f32x4 av[14];
        #pragma unroll
        for (int dx = 0; dx < 7; ++dx) {
            av[dx * 2]     = *(const f32x4*)&a_s[(dy * 7 + dx) * 64 + pg * 8];
            av[dx * 2 + 1] = *(const f32x4*)&a_s[(dy * 7 + dx) * 64 + pg * 8 + 4];
        }
        const short* krow = kbase + dy * KHB_W;
        #pragma unroll
        for (int c = 0; c < 8; ++c) {
            const short* kp = krow + (size_t)c * 32 * KHB_PLANE;
            bf16x8 k0 = *(const bf16x8*)(kp);
            bf16x8 k1 = *(const bf16x8*)(kp + 8);
            float win[16];
            #pragma unroll
            for (int t = 0; t < 8; ++t) { win[t] = bf2f(k0[t]); win[t + 8] = bf2f(k1[t]); }
            #pragma unroll
            for (int dx = 0; dx < 7; ++dx) {
                #pragma unroll
                for (int j = 0; j < 8; ++j)
                    acc[c][j] = fmaf(win[j + dx + 1], av[dx * 2 + (j >> 2)][j & 3],
                                     acc[c][j]);
            }
        }
    }

    #pragma unroll
    for (int c = 0; c < 8; ++c) {
        float* op = out + (((size_t)b * 256 + ci + c * 32) << 14) + (y << 7) + p0;
        f32x4 r0 = {acc[c][0], acc[c][1], acc[c][2], acc[c][3]};
        f32x4 r1 = {acc[c][4], acc[c][5], acc[c][6], acc[c][7]};
        *(f32x4*)op = r0;
        *(f32x4*)(op + 4) = r1;
    }
}

// ---------------------------------------------------------------------------
extern "C" void kernel_launch(void* const* d_in, const int* in_sizes, int n_in,
                              void* d_out, int out_size, void* d_ws, size_t ws_size,
                              hipStream_t stream) {
    (void)in_sizes; (void)n_in; (void)out_size; (void)ws_size;
    const float* cur_low  = (const float*)d_in[0];
    const float* key_low  = (const float*)d_in[1];
    const float* key_high = (const float*)d_in[2];
    const float* w_red    = (const float*)d_in[3];
    const float* b_red    = (const float*)d_in[4];
    const float* w2       = (const float*)d_in[5];
    const float* b2       = (const float*)d_in[6];
    const float* w3       = (const float*)d_in[7];
    const float* b3       = (const float*)d_in[8];
    float* out = (float*)d_out;
    char* ws = (char*)d_ws;

    const size_t SZ_XPAD = (size_t)BN * HP * HP * CLOW * 2;
    const size_t SZ_YPAD = (size_t)BN * HP * HP * CMID * 2;
    short* xpadc = (short*)(ws);
    short* xpadk = (short*)(ws + SZ_XPAD);
    short* ypadc = (short*)(ws + 2 * SZ_XPAD);
    short* ypadk = (short*)(ws + 2 * SZ_XPAD + SZ_YPAD);
    short* w1p   = (short*)(ws + 2 * SZ_XPAD + 2 * SZ_YPAD);
    short* w2p   = w1p + (size_t)256 * 1152;
    float* z     = (float*)(ws);
    short* khb   = (short*)(ws + 2 * SZ_XPAD);
    short* w3p   = (short*)((char*)d_out + (size_t)134217728 - 32768);

    hipFuncSetAttribute((const void*)conv_8ph_kernel<128, true, false>,
                        hipFuncAttributeMaxDynamicSharedMemorySize, 65536);
    hipFuncSetAttribute((const void*)conv_8ph_kernel<512, false, true>,
                        hipFuncAttributeMaxDynamicSharedMemorySize, 98304);

    zero_border_all_kernel<<<dim3(516, 4), 256, 0, stream>>>(xpadc, xpadk, ypadc, ypadk);
    convert_pad_kernel<<<dim3(1024, 2), 256, 0, stream>>>(cur_low, key_low, xpadc, xpadk);
    pack_w_all_kernel<<<(256 * (1152 + 4608) + 64 * 256 + 255) / 256, 256, 0, stream>>>(
        w_red, w1p, w2, w2p, w3, w3p);

    conv_8ph_kernel<128, true, false><<<dim3(512, 1, 2), 512, 65536, stream>>>(
        xpadc, xpadk, w1p, b_red, ypadc, ypadk, nullptr, nullptr, nullptr);

    conv_8ph_kernel<512, false, true><<<dim3(512, 1, 1), 512, 98304, stream>>>(
        ypadc, ypadk, w2p, b2, nullptr, nullptr, w3p, b3, z);

    pad_kh_kernel<<<2048, 256, 0, stream>>>(key_high, khb);
    svc4_kernel<<<dim3(2, 1024), 256, 0, stream>>>(z, khb, out);
}

// Round 15
// 633.413 us; speedup vs baseline: 1.5329x; 1.3850x over previous
//
#include <hip/hip_runtime.h>
#include <stdint.h>
#include <stddef.h>

#define BN   8
#define HN   128
#define WN   128
#define HP   130
#define CLOW 128
#define CMID 256
#define KO   49

// padded key_high (bf16): [b][c][134][144], khb[b][c][y+3][x+4] = kh[b][c][y][x]
#define KHB_H 134
#define KHB_W 144
#define KHB_PLANE (KHB_H * KHB_W)   // 19296 shorts

typedef __attribute__((ext_vector_type(4))) float f32x4;
typedef __attribute__((ext_vector_type(8))) short bf16x8;

typedef __attribute__((address_space(1))) const uint8_t ga_u8;
typedef __attribute__((address_space(3))) uint8_t lds_u8;

__device__ __forceinline__ short f2bf(float f) {
    uint32_t u = __float_as_uint(f);
    u += 0x7fffu + ((u >> 16) & 1u);
    return (short)(u >> 16);
}
__device__ __forceinline__ float bf2f(short s) {
    return __uint_as_float(((uint32_t)(uint16_t)s) << 16);
}
__device__ __forceinline__ void gload16(const void* g, void* l) {
    __builtin_amdgcn_global_load_lds((ga_u8*)g, (lds_u8*)l, 16, 0, 0);
}

// ---------------------------------------------------------------------------
// Zero halo cells of all four padded [b][130][130][C] bf16 buffers.
// ---------------------------------------------------------------------------
__global__ __launch_bounds__(256) void zero_border_all_kernel(
    short* __restrict__ b0, short* __restrict__ b1,
    short* __restrict__ b2, short* __restrict__ b3) {
    const int which = blockIdx.y;
    short* buf = (which == 0) ? b0 : (which == 1) ? b1 : (which == 2) ? b2 : b3;
    const int gsh = (which < 2) ? 4 : 5;
    const int C = (which < 2) ? 128 : 256;
    int t = blockIdx.x * 256 + threadIdx.x;
    int cell = t >> gsh, g = t & ((1 << gsh) - 1);
    if (cell >= 8 * 516) return;
    int b = cell / 516, r = cell - b * 516;
    int y, x;
    if (r < 260) { y = (r >= 130) ? 129 : 0; x = (r >= 130) ? (r - 130) : r; }
    else { int j = r - 260; y = 1 + (j >> 1); x = (j & 1) ? 129 : 0; }
    uint4 z = {0u, 0u, 0u, 0u};
    *(uint4*)&buf[(((size_t)b * HP + y) * HP + x) * C + g * 8] = z;
}

// ---------------------------------------------------------------------------
// Convert NCHW fp32 -> zero-padded NHWC bf16 ([b][130][130][128]).
// ---------------------------------------------------------------------------
__global__ __launch_bounds__(256) void convert_pad_kernel(
    const float* __restrict__ src0, const float* __restrict__ src1,
    short* __restrict__ dst0, short* __restrict__ dst1) {
    __shared__ short t[128 * 136];
    const int tid = threadIdx.x;
    const int by = blockIdx.x;
    const int b = by >> 7, y = by & 127;
    const float* src = blockIdx.y ? src1 : src0;
    short* dst = blockIdx.y ? dst1 : dst0;
    #pragma unroll
    for (int k = 0; k < 16; ++k) {
        int slot = k * 256 + tid;
        int c = slot >> 5, xg = slot & 31;
        f32x4 v = *(const f32x4*)&src[(((size_t)b * CLOW + c) * HN + y) * WN + xg * 4];
        #pragma unroll
        for (int j = 0; j < 4; ++j) t[(xg * 4 + j) * 136 + c] = f2bf(v[j]);
    }
    __syncthreads();
    short* drow = dst + (((size_t)b * HP + (y + 1)) * HP + 1) * CLOW;
    #pragma unroll
    for (int k = 0; k < 8; ++k) {
        int slot = k * 256 + tid;
        int x = slot >> 4, cg = slot & 15;
        *(bf16x8*)&drow[x * CLOW + cg * 8] = *(const bf16x8*)&t[x * 136 + cg * 8];
    }
}

// ---------------------------------------------------------------------------
// Pack all weights in one launch: w_red/w2 -> tap-inner K order (CB=64);
// w3 -> bf16 [64][256] (rows 49..63 zero).
// ---------------------------------------------------------------------------
__global__ __launch_bounds__(256) void pack_w_all_kernel(
    const float* __restrict__ w1, short* __restrict__ wp1,
    const float* __restrict__ w2, short* __restrict__ wp2,
    const float* __restrict__ w3, short* __restrict__ wp3) {
    int i = blockIdx.x * 256 + threadIdx.x;
    if (i < 256 * 1152 + 256 * 4608) {
        const float* w; short* wp; int CIN, K;
        if (i < 256 * 1152) { w = w1; wp = wp1; CIN = 128; K = 1152; }
        else { i -= 256 * 1152; w = w2; wp = wp2; CIN = 512; K = 4608; }
        int cout = i / K;
        int r = i - cout * K;
        int t = r >> 6;                  // CB = 64
        int j = r & 63;
        int cb = t / 9;
        int tap = t - cb * 9;
        int cin = cb * 64 + j;
        wp[i] = f2bf(w[((size_t)cout * CIN + cin) * 9 + tap]);
    } else {
        int j = i - (256 * 1152 + 256 * 4608);
        if (j >= 64 * 256) return;
        int o = j >> 8, ch = j & 255;
        wp3[j] = (o < KO) ? f2bf(w3[o * 256 + ch]) : (short)0;
    }
}

// ---------------------------------------------------------------------------
// Unified 3x3-conv 256x256x(BK=64) 8-phase kernel (T2+T3+T4+T5 template).
// ph0 issues ALL B reads (br0+br1) and waits lgkmcnt(4) only (br1 overlaps
// ph0's MFMA); ph1 waits lgkmcnt(0) with zero new reads.
// FUSE (conv2 only): MFMA-based fused 1x1(256->49[+b3]) epilogue writing
// fp32 logits z[pix][64] (coalesced); softmax runs fused in svc4.
// [Round-10 configuration — best measured: conv2f 326us, total 654us.]
// ---------------------------------------------------------------------------
template <int CIN, bool OPAD, bool FUSE>
__global__ __launch_bounds__(512, 2) void conv_8ph_kernel(
    const short* __restrict__ in_a, const short* __restrict__ in_b,
    const short* __restrict__ wp, const float* __restrict__ bias,
    short* __restrict__ out_a, short* __restrict__ out_b,
    const short* __restrict__ w3p, const float* __restrict__ b3,
    float* __restrict__ z) {
    constexpr int K = 9 * CIN;
    constexpr int NT = K / 64;
    constexpr bool DUAL = (CIN == 512);
    constexpr int PST = DUAL ? 256 : CIN;
    extern __shared__ __align__(16) short lds[];   // 131072 B
    const int tid = threadIdx.x;
    int bx = blockIdx.x;
    bx = (bx & 7) * 64 + (bx >> 3);
    const int b = bx >> 6, y0 = (bx & 63) << 1;
    const short* inA = DUAL ? in_a : (blockIdx.z ? in_b : in_a);
    const short* inB = DUAL ? in_b : inA;
    short* out = (!DUAL && blockIdx.z) ? out_b : out_a;

    const int lane = tid & 63, wv = tid >> 6;
    const int wm = wv >> 2, wn = wv & 3;
    const int lr = lane & 15, lk = lane >> 4;

    const int rA = tid >> 3, cc = tid & 7;
    const int cs = cc ^ (rA & 7);
    const int pthrA0 = rA * PST + cs * 8;
    const int pthrA1 = (rA + 64) * PST + cs * 8;
    const int pthrB0 = rA * K + cs * 8;
    const int pthrB1 = (rA + 64) * K + cs * 8;
    const int dA0 = rA * 64 + cc * 8;
    const int dB0 = rA * 64 + cc * 8;

    const int arow = (wm * 128 + lr) * 64;
    const int brow = (wn * 64 + lr) * 64;
    const int cof0 = ((lk) ^ (lr & 7)) * 8;
    const int cof1 = ((4 + lk) ^ (lr & 7)) * 8;

    f32x4 acc[8][4];
    f32x4 zero = {0.f, 0.f, 0.f, 0.f};
    #pragma unroll
    for (int i = 0; i < 8; ++i)
        #pragma unroll
        for (int j = 0; j < 4; ++j) acc[i][j] = zero;

    auto STAGE2 = [&](int t2, int which, short* bufA, short* bufB) {
        const int cb = (t2 * 57) >> 9;
        const int tap = t2 - cb * 9;
        const int ch0v = cb << 6;
        const short* src = (!DUAL || ch0v < 256) ? inA : inB;
        const int ch0 = DUAL ? (ch0v & 255) : ch0v;
        const int ky = (tap * 11) >> 5;
        const int kx = tap - ky * 3;
        if (which == 0 || which == 2) {
            const int po = (which == 0) ? pthrA0 : pthrA1;
            const int doff = (which == 0) ? 0 : 64 * 64;
            const short* s0 = src + ((size_t)(b * HP + (y0 + ky)) * HP + kx) * PST + ch0;
            gload16(s0 + po, bufA + doff + dA0);
            gload16(s0 + (HP * PST) + po, bufA + 128 * 64 + doff + dA0);
        } else {
            const int h2 = (which == 1) ? 0 : 1;
            const short* sb = wp + (size_t)(h2 * 128) * K + t2 * 64;
            short* d = bufB + h2 * 128 * 64 + dB0;
            gload16(sb + pthrB0, d);
            gload16(sb + pthrB1, d + 64 * 64);
        }
    };

    auto LDA = [&](const short* bufA, int mh, bf16x8 (&a)[4][2]) {
        #pragma unroll
        for (int i = 0; i < 4; ++i) {
            const int ro = arow + (mh * 64 + i * 16) * 64;
            a[i][0] = *(const bf16x8*)(bufA + ro + cof0);
            a[i][1] = *(const bf16x8*)(bufA + ro + cof1);
        }
    };
    auto LDB = [&](const short* bufB, int nh, bf16x8 (&bb)[2][2]) {
        #pragma unroll
        for (int j = 0; j < 2; ++j) {
            const int ro = brow + (nh * 32 + j * 16) * 64;
            bb[j][0] = *(const bf16x8*)(bufB + ro + cof0);
            bb[j][1] = *(const bf16x8*)(bufB + ro + cof1);
        }
    };

#define PH_PRE4() do { __builtin_amdgcn_sched_barrier(0); \
                       __builtin_amdgcn_s_barrier(); \
                       asm volatile("s_waitcnt lgkmcnt(4)" ::: "memory"); \
                       __builtin_amdgcn_sched_barrier(0); \
                       __builtin_amdgcn_s_setprio(1); } while (0)
#define PH_PRE() do { __builtin_amdgcn_sched_barrier(0); \
                      __builtin_amdgcn_s_barrier(); \
                      asm volatile("s_waitcnt lgkmcnt(0)" ::: "memory"); \
                      __builtin_amdgcn_sched_barrier(0); \
                      __builtin_amdgcn_s_setprio(1); } while (0)
#define PH_POST() do { __builtin_amdgcn_s_setprio(0); \
                       __builtin_amdgcn_sched_barrier(0); \
                       __builtin_amdgcn_s_barrier(); } while (0)
#define MFMA_Q(A_, B_, MH, NH) do { \
    _Pragma("unroll") \
    for (int i_ = 0; i_ < 4; ++i_) { \
        _Pragma("unroll") \
        for (int j_ = 0; j_ < 2; ++j_) { \
            acc[(MH)*4+i_][(NH)*2+j_] = __builtin_amdgcn_mfma_f32_16x16x32_bf16( \
                A_[i_][0], B_[j_][0], acc[(MH)*4+i_][(NH)*2+j_], 0, 0, 0); \
            acc[(MH)*4+i_][(NH)*2+j_] = __builtin_amdgcn_mfma_f32_16x16x32_bf16( \
                A_[i_][1], B_[j_][1], acc[(MH)*4+i_][(NH)*2+j_], 0, 0, 0); \
        } \
    } } while (0)

    short* const A0 = lds;
    short* const A1 = lds + 16384;
    short* const B0 = lds + 32768;
    short* const B1 = lds + 49152;

    STAGE2(0, 0, A0, B0); STAGE2(0, 1, A0, B0);
    STAGE2(0, 2, A0, B0); STAGE2(0, 3, A0, B0);
    STAGE2(1, 0, A1, B1); STAGE2(1, 1, A1, B1);
    STAGE2(1, 2, A1, B1); STAGE2(1, 3, A1, B1);
    asm volatile("s_waitcnt vmcnt(8)" ::: "memory");
    __builtin_amdgcn_sched_barrier(0);
    __builtin_amdgcn_s_barrier();

    auto TILE = [&](int t, short* bufA, short* bufB) {
        const int t2 = t + 2;
        const bool st = (t2 < NT);
        bf16x8 ar[4][2], br0[2][2], br1[2][2];
        // phase 0 (mh=0, nh=0): issue A(mh0)+B(nh0)+B(nh1); wait first 12 only
        LDA(bufA, 0, ar);
        LDB(bufB, 0, br0);
        LDB(bufB, 1, br1);
        if (st) STAGE2(t2, 0, bufA, bufB);
        PH_PRE4();
        MFMA_Q(ar, br0, 0, 0);
        PH_POST();
        // phase 1 (mh=0, nh=1): no new reads; br1 already resident
        if (st) STAGE2(t2, 1, bufA, bufB);
        PH_PRE();
        MFMA_Q(ar, br1, 0, 1);
        PH_POST();
        // phase 2 (mh=1, nh=0)
        LDA(bufA, 1, ar);
        if (st) STAGE2(t2, 2, bufA, bufB);
        PH_PRE();
        MFMA_Q(ar, br0, 1, 0);
        PH_POST();
        // phase 3 (mh=1, nh=1)
        if (st) STAGE2(t2, 3, bufA, bufB);
        PH_PRE();
        MFMA_Q(ar, br1, 1, 1);
        __builtin_amdgcn_s_setprio(0);
        __builtin_amdgcn_sched_barrier(0);
        if (st)                asm volatile("s_waitcnt vmcnt(8)" ::: "memory");
        else if (t == NT - 2)  asm volatile("s_waitcnt vmcnt(0)" ::: "memory");
        __builtin_amdgcn_sched_barrier(0);
        __builtin_amdgcn_s_barrier();
    };

    for (int t = 0; t < NT; t += 2) {
        TILE(t,     A0, B0);
        TILE(t + 1, A1, B1);
    }
#undef PH_PRE4
#undef PH_PRE
#undef PH_POST
#undef MFMA_Q

    float bvs[4];
    #pragma unroll
    for (int nf = 0; nf < 4; ++nf) bvs[nf] = bias[wn * 64 + nf * 16 + lr];

    if constexpr (!FUSE) {
        // plain epilogue: bias+ReLU -> NHWC bf16, nf-innermost stores
        #pragma unroll
        for (int mf = 0; mf < 8; ++mf) {
            #pragma unroll
            for (int rr = 0; rr < 4; ++rr) {
                const int p = wm * 128 + mf * 16 + lk * 4 + rr;
                const int y = y0 + (p >> 7), x = p & 127;
                short* op;
                if (OPAD)
                    op = out + ((size_t)(b * HP + (y + 1)) * HP + (x + 1)) * CMID + wn * 64 + lr;
                else
                    op = out + ((size_t)((b * HN + y) * WN + x)) * CMID + wn * 64 + lr;
                #pragma unroll
                for (int nf = 0; nf < 4; ++nf)
                    op[nf * 16] = f2bf(fmaxf(acc[mf][nf][rr] + bvs[nf], 0.f));
            }
        }
    } else {
        // ---- MFMA 1x1(256->49) epilogue: logits -> z[pix][64] fp32 ----
        short* const Xh  = lds;                        // [128px][256ch] bf16 swz
        short* const W3s = lds + 32768;                // [64o][256ch] bf16 swz

        // stage w3p -> W3s (LDS linear dest, inverse-swizzled global source)
        #pragma unroll
        for (int sweep = 0; sweep < 4; ++sweep) {
            const int s = sweep * 512 + tid;
            const int o = s >> 5, c = s & 31;
            gload16(w3p + o * 256 + ((c ^ (o & 7)) << 3), W3s + s * 8);
        }

        const int oo = wn * 16 + lr;                    // this lane's output idx
        const float b3v = (oo < KO) ? b3[oo] : 0.f;

        #pragma unroll 1
        for (int r = 0; r < 2; ++r) {
            // 1) waves wm==r deposit their px-half as bf16 (bias+ReLU), swz
            if (wm == r) {
                #pragma unroll
                for (int nf = 0; nf < 4; ++nf) {
                    const int ch = wn * 64 + nf * 16 + lr;
                    const int ck = ch >> 3, el = ch & 7;
                    #pragma unroll
                    for (int mf = 0; mf < 8; ++mf) {
                        #pragma unroll
                        for (int rr = 0; rr < 4; ++rr) {
                            const int px = mf * 16 + lk * 4 + rr;
                            Xh[px * 256 + ((ck ^ (px & 7)) << 3) + el] =
                                f2bf(fmaxf(acc[mf][nf][rr] + bvs[nf], 0.f));
                        }
                    }
                }
            }
            __syncthreads();
            // 2) GEMM [128px x 256ch] x [64o x 256ch]^T, C init = b3
            f32x4 a2[4];
            #pragma unroll
            for (int m = 0; m < 4; ++m) {
                a2[m][0] = b3v; a2[m][1] = b3v; a2[m][2] = b3v; a2[m][3] = b3v;
            }
            #pragma unroll
            for (int ks = 0; ks < 8; ++ks) {
                const bf16x8 bfr =
                    *(const bf16x8*)&W3s[oo * 256 + (((ks * 4 + lk) ^ (oo & 7)) << 3)];
                #pragma unroll
                for (int m = 0; m < 4; ++m) {
                    const int px = wm * 64 + m * 16 + lr;
                    const bf16x8 afr =
                        *(const bf16x8*)&Xh[px * 256 + (((ks * 4 + lk) ^ (px & 7)) << 3)];
                    a2[m] = __builtin_amdgcn_mfma_f32_16x16x32_bf16(afr, bfr, a2[m], 0, 0, 0);
                }
            }
            // 3) D -> z (coalesced 64B runs: lr->oo consecutive)
            float* zp = z + ((size_t)(b * 16384 + (y0 + r) * 128)) * 64;
            #pragma unroll
            for (int m = 0; m < 4; ++m) {
                #pragma unroll
                for (int r2 = 0; r2 < 4; ++r2) {
                    const int px = wm * 64 + m * 16 + lk * 4 + r2;
                    zp[px * 64 + oo] = a2[m][r2];
                }
            }
            if (r == 0) __syncthreads();   // all Xh reads done before re-deposit
        }
    }
}

// ---------------------------------------------------------------------------
// Pad key_high NCHW fp32 -> bf16 [b][c][134][144] with zero halo, vectorized:
// per (row,group) unit: two aligned f32x4 loads + one bf16x8 store.
// ---------------------------------------------------------------------------
__global__ __launch_bounds__(256) void pad_kh_kernel(
    const float* __restrict__ kh, short* __restrict__ khb) {
    const int bc = blockIdx.x;
    const float* src = kh + (size_t)bc * (HN * WN);
    short* dst = khb + (size_t)bc * KHB_PLANE;
    for (int u = threadIdx.x; u < KHB_H * 18; u += 256) {
        const int yy = (u * 3641) >> 16;          // u/18 for u < 2412
        const int g = u - yy * 18;
        const int ys = yy - 3;
        const int xb = g * 8 - 4;                 // kh x of output elem 0
        f32x4 lo = {0.f, 0.f, 0.f, 0.f}, hi = {0.f, 0.f, 0.f, 0.f};
        if ((unsigned)ys < 128u) {
            const float* row = src + (ys << 7);
            if ((unsigned)xb < 125u)       lo = *(const f32x4*)(row + xb);
            if ((unsigned)(xb + 4) < 125u) hi = *(const f32x4*)(row + xb + 4);
        }
        bf16x8 v;
        #pragma unroll
        for (int t = 0; t < 4; ++t) { v[t] = f2bf(lo[t]); v[t + 4] = f2bf(hi[t]); }
        *(bf16x8*)&dst[yy * KHB_W + g * 8] = v;
    }
}

// ---------------------------------------------------------------------------
// SVC v4: fused softmax (from z logits) + spatially-variant conv.
// ---------------------------------------------------------------------------
__global__ __launch_bounds__(256) void svc4_kernel(
    const float* __restrict__ z, const short* __restrict__ khb,
    float* __restrict__ out) {
    __shared__ float a_s[KO * 64];
    const int tid = threadIdx.x;
    int by = blockIdx.y;
    by = (by & 7) * 128 + (by >> 3);
    const int b = by >> 7, y = by & 127;
    const int x0 = blockIdx.x * 64;

    {
        const int px = tid >> 2, l = tid & 3;
        const float* zp = z + ((size_t)(b * 16384 + (y << 7) + x0 + px)) * 64 + l * 16;
        float v[16];
        #pragma unroll
        for (int q = 0; q < 4; ++q) {
            f32x4 t4 = *(const f32x4*)&zp[q * 4];
            v[q * 4 + 0] = fmaxf(t4[0], 0.f);
            v[q * 4 + 1] = fmaxf(t4[1], 0.f);
            v[q * 4 + 2] = fmaxf(t4[2], 0.f);
            v[q * 4 + 3] = fmaxf(t4[3], 0.f);
        }
        #pragma unroll
        for (int j = 1; j < 16; ++j) if (l == 3) v[j] = -1e30f;
        float m = v[0];
        #pragma unroll
        for (int j = 1; j < 16; ++j) m = fmaxf(m, v[j]);
        m = fmaxf(m, __shfl_xor(m, 1, 64));
        m = fmaxf(m, __shfl_xor(m, 2, 64));
        float s = 0.f;
        #pragma unroll
        for (int j = 0; j < 16; ++j) { v[j] = __expf(v[j] - m); s += v[j]; }
        s += __shfl_xor(s, 1, 64);
        s += __shfl_xor(s, 2, 64);
        const float inv = 1.f / s;
        #pragma unroll
        for (int j = 0; j < 16; ++j) {
            const int o = l * 16 + j;
            if (o < KO) a_s[o * 64 + px] = v[j] * inv;
        }
    }
    __syncthreads();

    const int ci = tid >> 3;
    const int pg = tid & 7;
    const int p0 = x0 + pg * 8;

    float acc[8][8];
    #pragma unroll
    for (int c = 0; c < 8; ++c)
        #pragma unroll
        for (int j = 0; j < 8; ++j) acc[c][j] = 0.f;

    const short* kbase = khb + (((size_t)b * 256 + ci) * KHB_H + y) * KHB_W + p0;

    #pragma unroll 1
    for (int dy = 0; dy < 7; ++dy) {
        f32x4 av[14];
        #pragma unroll
        for (int dx = 0; dx < 7; ++dx) {
            av[dx * 2]     = *(const f32x4*)&a_s[(dy * 7 + dx) * 64 + pg * 8];
            av[dx * 2 + 1] = *(const f32x4*)&a_s[(dy * 7 + dx) * 64 + pg * 8 + 4];
        }
        const short* krow = kbase + dy * KHB_W;
        #pragma unroll
        for (int c = 0; c < 8; ++c) {
            const short* kp = krow + (size_t)c * 32 * KHB_PLANE;
            bf16x8 k0 = *(const bf16x8*)(kp);
            bf16x8 k1 = *(const bf16x8*)(kp + 8);
            float win[16];
            #pragma unroll
            for (int t = 0; t < 8; ++t) { win[t] = bf2f(k0[t]); win[t + 8] = bf2f(k1[t]); }
            #pragma unroll
            for (int dx = 0; dx < 7; ++dx) {
                #pragma unroll
                for (int j = 0; j < 8; ++j)
                    acc[c][j] = fmaf(win[j + dx + 1], av[dx * 2 + (j >> 2)][j & 3],
                                     acc[c][j]);
            }
        }
    }

    #pragma unroll
    for (int c = 0; c < 8; ++c) {
        float* op = out + (((size_t)b * 256 + ci + c * 32) << 14) + (y << 7) + p0;
        f32x4 r0 = {acc[c][0], acc[c][1], acc[c][2], acc[c][3]};
        f32x4 r1 = {acc[c][4], acc[c][5], acc[c][6], acc[c][7]};
        *(f32x4*)op = r0;
        *(f32x4*)(op + 4) = r1;
    }
}

// ---------------------------------------------------------------------------
extern "C" void kernel_launch(void* const* d_in, const int* in_sizes, int n_in,
                              void* d_out, int out_size, void* d_ws, size_t ws_size,
                              hipStream_t stream) {
    (void)in_sizes; (void)n_in; (void)out_size; (void)ws_size;
    const float* cur_low  = (const float*)d_in[0];
    const float* key_low  = (const float*)d_in[1];
    const float* key_high = (const float*)d_in[2];
    const float* w_red    = (const float*)d_in[3];
    const float* b_red    = (const float*)d_in[4];
    const float* w2       = (const float*)d_in[5];
    const float* b2       = (const float*)d_in[6];
    const float* w3       = (const float*)d_in[7];
    const float* b3       = (const float*)d_in[8];
    float* out = (float*)d_out;
    char* ws = (char*)d_ws;

    const size_t SZ_XPAD = (size_t)BN * HP * HP * CLOW * 2;
    const size_t SZ_YPAD = (size_t)BN * HP * HP * CMID * 2;
    short* xpadc = (short*)(ws);
    short* xpadk = (short*)(ws + SZ_XPAD);
    short* ypadc = (short*)(ws + 2 * SZ_XPAD);
    short* ypadk = (short*)(ws + 2 * SZ_XPAD + SZ_YPAD);
    short* w1p   = (short*)(ws + 2 * SZ_XPAD + 2 * SZ_YPAD);
    short* w2p   = w1p + (size_t)256 * 1152;
    float* z     = (float*)(ws);
    short* khb   = (short*)(ws + 2 * SZ_XPAD);
    short* w3p   = (short*)((char*)d_out + (size_t)134217728 - 32768);

    hipFuncSetAttribute((const void*)conv_8ph_kernel<128, true, false>,
                        hipFuncAttributeMaxDynamicSharedMemorySize, 131072);
    hipFuncSetAttribute((const void*)conv_8ph_kernel<512, false, true>,
                        hipFuncAttributeMaxDynamicSharedMemorySize, 131072);

    zero_border_all_kernel<<<dim3(516, 4), 256, 0, stream>>>(xpadc, xpadk, ypadc, ypadk);
    convert_pad_kernel<<<dim3(1024, 2), 256, 0, stream>>>(cur_low, key_low, xpadc, xpadk);
    pack_w_all_kernel<<<(256 * (1152 + 4608) + 64 * 256 + 255) / 256, 256, 0, stream>>>(
        w_red, w1p, w2, w2p, w3, w3p);

    conv_8ph_kernel<128, true, false><<<dim3(512, 1, 2), 512, 131072, stream>>>(
        xpadc, xpadk, w1p, b_red, ypadc, ypadk, nullptr, nullptr, nullptr);

    conv_8ph_kernel<512, false, true><<<dim3(512, 1, 1), 512, 131072, stream>>>(
        ypadc, ypadk, w2p, b2, nullptr, nullptr, w3p, b3, z);

    pad_kh_kernel<<<2048, 256, 0, stream>>>(key_high, khb);
    svc4_kernel<<<dim3(2, 1024), 256, 0, stream>>>(z, khb, out);
}